// Round 1
// baseline (141.688 us; speedup 1.0000x reference)
//
#include <hip/hip_runtime.h>

#define Zdim 128
#define Ydim 512
#define Xdim 512
#define Pdim 15
#define NWt  19   // 4 spatial + 15 spectral weights per z

// One thread per (y,x) pixel; marches z=0..127 keeping a 15-deep register
// shift-ring of previous center values for the spectral term.
__global__ __launch_bounds__(256) void spec_pred_kernel(
    const float* __restrict__ img,
    const float* __restrict__ wts,
    float* __restrict__ out)
{
    __shared__ float sw[Zdim * NWt];   // 9728 B
    for (int i = threadIdx.x; i < Zdim * NWt; i += 256)
        sw[i] = wts[i];
    __syncthreads();

    const int idx = blockIdx.x * 256 + threadIdx.x;   // 0 .. 262143
    const int x = idx & (Xdim - 1);
    const int y = idx >> 9;                           // Xdim = 512

    const size_t plane = (size_t)Ydim * Xdim;
    const size_t pix   = (size_t)y * Xdim + x;

    const bool hn = (y > 0);
    const bool hw = (x > 0);

    float h[Pdim];                                    // spectral history ring
#pragma unroll
    for (int p = 0; p < Pdim; ++p) h[p] = 0.0f;

    float* __restrict__ pred_out = out;
    float* __restrict__ res_out  = out + (size_t)Zdim * plane;

    for (int z = 0; z < Zdim; ++z) {
        const float* p0 = img + (size_t)z * plane + pix;
        const float cur = p0[0];
        const float vn  = hn        ? p0[-Xdim]     : 0.0f;
        const float vw  = hw        ? p0[-1]        : 0.0f;
        const float vnw = (hn && hw) ? p0[-Xdim - 1] : 0.0f;

        const float* wz = &sw[z * NWt];               // wave-uniform LDS reads
        const float w3 = wz[3] * (1.0f / 3.0f);
        float acc = (wz[0] + w3) * vn;
        acc = fmaf(wz[1] + w3, vw,  acc);
        acc = fmaf(wz[2] + w3, vnw, acc);
#pragma unroll
        for (int p = 0; p < Pdim; ++p)
            acc = fmaf(wz[4 + p], h[p], acc);

        // shift history (static indexing — stays in registers)
#pragma unroll
        for (int p = 0; p < Pdim - 1; ++p) h[p] = h[p + 1];
        h[Pdim - 1] = cur;

        acc = fminf(fmaxf(acc, -32768.0f), 32767.0f);
        pred_out[(size_t)z * plane + pix] = acc;
        res_out [(size_t)z * plane + pix] = cur - acc;
    }
}

extern "C" void kernel_launch(void* const* d_in, const int* in_sizes, int n_in,
                              void* d_out, int out_size, void* d_ws, size_t ws_size,
                              hipStream_t stream) {
    const float* img = (const float*)d_in[0];
    const float* wts = (const float*)d_in[1];
    float* out = (float*)d_out;

    const int threads = 256;
    const int grid = (Ydim * Xdim) / threads;   // 1024 blocks
    spec_pred_kernel<<<grid, threads, 0, stream>>>(img, wts, out);
}

// Round 2
// 83.731 us; speedup vs baseline: 1.6922x; 1.6922x over previous
//
#include <hip/hip_runtime.h>

#define Zdim 128
#define Ydim 512
#define Xdim 512
#define Pdim 15
#define NWt  19
#define CHUNK 32          // z-planes per block; 4 chunks

typedef __attribute__((ext_vector_type(4))) float f4;
struct F4 { float v[4]; };

__device__ __forceinline__ F4 ld4(const float* p) {
    f4 t = *(const f4*)p;
    F4 r; r.v[0] = t[0]; r.v[1] = t[1]; r.v[2] = t[2]; r.v[3] = t[3];
    return r;
}

// One thread per 4 consecutive x; marches CHUNK z-planes with a 15-deep
// register history ring and a 2-stage load/compute software pipeline.
__global__ __launch_bounds__(256, 4) void spec_pred_kernel(
    const float* __restrict__ img,
    const float* __restrict__ wts,
    float* __restrict__ out)
{
    __shared__ float sw[Zdim * NWt];
    for (int i = threadIdx.x; i < Zdim * NWt; i += 256) sw[i] = wts[i];
    __syncthreads();

    const int bid = blockIdx.x;
    const int zc  = bid >> 8;                          // 0..3
    const int id  = ((bid & 255) << 8) | threadIdx.x;  // 0..65535
    const int xg  = (id & 127) << 2;                   // x0 of the float4
    const int y   = id >> 7;

    const size_t plane = (size_t)Ydim * Xdim;
    const size_t pix   = (size_t)y * Xdim + xg;
    const float* ip = img + pix;
    float* pp = out + pix;
    float* rp = out + (size_t)Zdim * plane + pix;

    const int  z0 = zc * CHUNK;
    const bool hn = (y > 0);
    const bool hw = (xg > 0);

    F4 h[Pdim];                                        // spectral history ring
    if (z0 == 0) {
#pragma unroll
        for (int p = 0; p < Pdim; ++p) h[p] = F4{{0, 0, 0, 0}};
    } else {
#pragma unroll
        for (int p = 0; p < Pdim; ++p)
            h[p] = ld4(ip + (size_t)(z0 - Pdim + p) * plane);
    }

    F4 c0, n0, c1, n1;
    float we0, nw0, we1, nw1;

    auto LOAD = [&](int z, F4& c, F4& n, float& we, float& nw) {
        const float* p0 = ip + (size_t)z * plane;
        c  = ld4(p0);
        n  = hn ? ld4(p0 - Xdim) : F4{{0, 0, 0, 0}};
        we = hw ? p0[-1] : 0.0f;
        nw = (hn && hw) ? p0[-Xdim - 1] : 0.0f;
    };

    auto STEP = [&](int z, const F4& c, const F4& n, float we, float nw) {
        const float* wz = &sw[z * NWt];                // wave-uniform LDS reads
        const float w3 = wz[3] * (1.0f / 3.0f);
        const float a0 = wz[0] + w3, a1 = wz[1] + w3, a2 = wz[2] + w3;
        f4 pv, rv;
#pragma unroll
        for (int e = 0; e < 4; ++e) {
            const float vn = n.v[e];
            const float vw = e ? c.v[e - 1] : we;
            const float vq = e ? n.v[e - 1] : nw;
            float a = a0 * vn;
            a = fmaf(a1, vw, a);
            a = fmaf(a2, vq, a);
#pragma unroll
            for (int p = 0; p < Pdim; ++p) a = fmaf(wz[4 + p], h[p].v[e], a);
            a = fminf(fmaxf(a, -32768.0f), 32767.0f);
            pv[e] = a;
            rv[e] = c.v[e] - a;
        }
        __builtin_nontemporal_store(pv, (f4*)(pp + (size_t)z * plane));
        __builtin_nontemporal_store(rv, (f4*)(rp + (size_t)z * plane));
#pragma unroll
        for (int p = 0; p < Pdim - 1; ++p) h[p] = h[p + 1];
        h[Pdim - 1] = c;
    };

    LOAD(z0, c0, n0, we0, nw0);
    for (int i = 0; i < CHUNK; i += 2) {
        const int z = z0 + i;
        LOAD(z + 1, c1, n1, we1, nw1);                 // prefetch odd plane
        STEP(z, c0, n0, we0, nw0);
        if (i + 2 < CHUNK) LOAD(z + 2, c0, n0, we0, nw0);  // prefetch next even
        STEP(z + 1, c1, n1, we1, nw1);
    }
}

extern "C" void kernel_launch(void* const* d_in, const int* in_sizes, int n_in,
                              void* d_out, int out_size, void* d_ws, size_t ws_size,
                              hipStream_t stream) {
    const float* img = (const float*)d_in[0];
    const float* wts = (const float*)d_in[1];
    float* out = (float*)d_out;

    const int grid = 256 * (Zdim / CHUNK);   // 1024 blocks of 256 threads
    spec_pred_kernel<<<grid, 256, 0, stream>>>(img, wts, out);
}

// Round 3
// 79.416 us; speedup vs baseline: 1.7841x; 1.0543x over previous
//
#include <hip/hip_runtime.h>

#define Zdim 128
#define Ydim 512
#define Xdim 512
#define Pdim 15
#define NWt  19
#define CHUNK 32          // z-planes per block; 4 chunks

typedef __attribute__((ext_vector_type(4))) float f4;
struct F4 { float v[4]; };

__device__ __forceinline__ F4 ld4(const float* p) {
    f4 t = *(const f4*)p;
    F4 r; r.v[0] = t[0]; r.v[1] = t[1]; r.v[2] = t[2]; r.v[3] = t[3];
    return r;
}

// One thread per 4 consecutive x; marches CHUNK z-planes.
// - 15-deep register history ring (static indexing; shifts amortized by unroll 6)
// - weights read via wave-uniform global addresses -> compiler emits s_load
//   into SGPRs (no LDS, no per-lane weight traffic)
// - 3-buffer, distance-2 software prefetch pipeline
__global__ __launch_bounds__(256, 4) void spec_pred_kernel(
    const float* __restrict__ img,
    const float* __restrict__ wts,
    float* __restrict__ out)
{
    const int bid = blockIdx.x;
    const int zc  = bid >> 8;                          // 0..3
    const int id  = ((bid & 255) << 8) | threadIdx.x;  // 0..65535
    const int xg  = (id & 127) << 2;                   // x0 of the float4
    const int y   = id >> 7;

    const size_t plane = (size_t)Ydim * Xdim;
    const size_t pix   = (size_t)y * Xdim + xg;
    const float* ip = img + pix;
    float* pp = out + pix;
    float* rp = out + (size_t)Zdim * plane + pix;

    const int  z0 = zc * CHUNK;
    const bool hn = (y > 0);
    const bool hw = (xg > 0);

    F4 h[Pdim];                                        // spectral history ring
    if (z0 == 0) {
#pragma unroll
        for (int p = 0; p < Pdim; ++p) h[p] = F4{{0, 0, 0, 0}};
    } else {
#pragma unroll
        for (int p = 0; p < Pdim; ++p)
            h[p] = ld4(ip + (size_t)(z0 - Pdim + p) * plane);
    }

    F4 cb[3], nb[3];                                   // rotating load buffers
    float wb[3], qb[3];                                // west / northwest edges

    auto LOAD = [&](int z, int b) {
        const float* p0 = ip + (size_t)z * plane;
        cb[b] = ld4(p0);
        nb[b] = hn ? ld4(p0 - Xdim) : F4{{0, 0, 0, 0}};
        wb[b] = hw ? p0[-1] : 0.0f;
        qb[b] = (hn && hw) ? p0[-Xdim - 1] : 0.0f;
    };

    auto STEP = [&](int z, int b) {
        const float* wz = wts + z * NWt;               // uniform addr -> s_load
        const float w3 = wz[3] * (1.0f / 3.0f);
        const float a0 = wz[0] + w3, a1 = wz[1] + w3, a2 = wz[2] + w3;
        f4 pv, rv;
#pragma unroll
        for (int e = 0; e < 4; ++e) {
            const float vn = nb[b].v[e];
            const float vw = e ? cb[b].v[e - 1] : wb[b];
            const float vq = e ? nb[b].v[e - 1] : qb[b];
            float a = a0 * vn;
            a = fmaf(a1, vw, a);
            a = fmaf(a2, vq, a);
#pragma unroll
            for (int p = 0; p < Pdim; ++p) a = fmaf(wz[4 + p], h[p].v[e], a);
            a = fminf(fmaxf(a, -32768.0f), 32767.0f);
            pv[e] = a;
            rv[e] = cb[b].v[e] - a;
        }
        __builtin_nontemporal_store(pv, (f4*)(pp + (size_t)z * plane));
        __builtin_nontemporal_store(rv, (f4*)(rp + (size_t)z * plane));
#pragma unroll
        for (int p = 0; p < Pdim - 1; ++p) h[p] = h[p + 1];
        h[Pdim - 1] = cb[b];
    };

    LOAD(z0 + 0, 0);
    LOAD(z0 + 1, 1);
#pragma unroll 6
    for (int i = 0; i < CHUNK - 2; ++i) {              // 30 iters, 6 | 30
        LOAD(z0 + i + 2, (i + 2) % 3);                 // distance-2 prefetch
        STEP(z0 + i, i % 3);
    }
    STEP(z0 + CHUNK - 2, (CHUNK - 2) % 3);
    STEP(z0 + CHUNK - 1, (CHUNK - 1) % 3);
}

extern "C" void kernel_launch(void* const* d_in, const int* in_sizes, int n_in,
                              void* d_out, int out_size, void* d_ws, size_t ws_size,
                              hipStream_t stream) {
    const float* img = (const float*)d_in[0];
    const float* wts = (const float*)d_in[1];
    float* out = (float*)d_out;

    const int grid = 256 * (Zdim / CHUNK);   // 1024 blocks of 256 threads
    spec_pred_kernel<<<grid, 256, 0, stream>>>(img, wts, out);
}